// Round 13
// baseline (694.190 us; speedup 1.0000x reference)
//
#include <hip/hip_runtime.h>
#include <hip/hip_bf16.h>

// AKT forward, round 13: split-K=2 for all N=1024 GEMMs (grid 1024 blocks =
// 4 blocks/CU; f32 two-buffer partials + sum/bias/GELU epilogue kernel),
// K-loop reverted to the round-10 single-buffer 2-barrier form (best measured).
// kv-GEMM stays direct (already 4/CU). Attn unchanged.
//   - glo term dropped (softmax-invariant per-query constant)
//   - pos_key folded into kv-GEMM epilogue
// Workspace (~132 MB): Xc 8M | X,Qb,Kp,Vp 4M | Winb 2M | Wall 24M | P 8M f32

#define B_ 4
#define S_ 1024
#define E_ 1024
#define H_ 16
#define D_ 64
#define L_ 4
#define M_ (B_ * S_)  // 4096
#define EE (E_ * E_)  // 1M

typedef __attribute__((ext_vector_type(8))) __bf16 bf16x8;
typedef __attribute__((ext_vector_type(4))) __bf16 bf16x4;
typedef __attribute__((ext_vector_type(4))) float f32x4;
typedef __attribute__((ext_vector_type(8))) unsigned short u16x8;

__device__ __forceinline__ float bf2f(unsigned short u) {
    union { unsigned int i; float f; } x;
    x.i = ((unsigned int)u) << 16;
    return x.f;
}
__device__ __forceinline__ float gelu_exact(float x) {
    return 0.5f * x * (1.0f + erff(x * 0.70710678118654752f));
}

// Packed K layout: frag=((bh*16+kt)*4+kb)*2+kc, elem=lane*8+j.
__device__ __forceinline__ size_t kpack_idx(int m, int col) {
    const int b = m >> 10, srow = m & (S_ - 1);
    const int h = col >> 6, d = col & 63;
    const int bh = b * H_ + h;
    const int kt = srow >> 6, kb = (srow >> 4) & 3, l15 = srow & 15;
    const int kc = d >> 5, lhi = (d >> 3) & 3, j = d & 7;
    const int frag = ((bh * 16 + kt) * 4 + kb) * 2 + kc;
    return (size_t)frag * 512 + (size_t)(lhi * 16 + l15) * 8 + j;
}
// Packed V layout (key-permuted to match P^T B-fragments).
__device__ __forceinline__ size_t vpack_idx(int m, int col) {
    const int b = m >> 10, key = m & (S_ - 1);
    const int h = col >> 6, d = col & 63;
    const int bh = b * H_ + h;
    const int kt = key >> 6;
    const int k6 = key & 63;
    const int kc = k6 >> 5, kl = k6 & 31;
    const int lhi = (kl >> 2) & 3;
    const int j = ((kl >> 4) << 2) | (kl & 3);
    const int db = d >> 4, l15 = d & 15;
    const int frag = ((bh * 16 + kt) * 4 + db) * 2 + kc;
    return (size_t)frag * 512 + (size_t)(lhi * 16 + l15) * 8 + j;
}

// ---------------------------------------------------------------------------
// f32 -> bf16 bulk convert (W_in)
// ---------------------------------------------------------------------------
__global__ __launch_bounds__(256) void cvt_f32_bf16(
    const float* __restrict__ in, __bf16* __restrict__ out, int n) {
    const int i = (blockIdx.x * 256 + threadIdx.x) * 4;
    if (i >= n) return;
    const float4 v = *(const float4*)(in + i);
    __bf16* o = out + i;
    o[0] = (__bf16)v.x; o[1] = (__bf16)v.y; o[2] = (__bf16)v.z; o[3] = (__bf16)v.w;
}

// ALL layers: Wq,Wk,Wv,Wl (L_ layers, 6 matrices each) -> Wall[24M] bf16
__global__ __launch_bounds__(256) void cvt_all_weights(
    const float* __restrict__ Wq, const float* __restrict__ Wk,
    const float* __restrict__ Wv, const float* __restrict__ Wl,
    __bf16* __restrict__ out) {
    const int i = (blockIdx.x * 256 + threadIdx.x) * 4;  // < 24M
    const int l = i / (6 * EE);
    const int r = i - l * 6 * EE;
    const int mat = r >> 20;
    const int off = r & (EE - 1);
    const float* src = (mat == 0) ? Wq + (size_t)l * EE
                     : (mat == 1) ? Wk + (size_t)l * EE
                     : (mat == 2) ? Wv + (size_t)l * EE
                                  : Wl + ((size_t)l * 3 + (mat - 3)) * EE;
    const float4 v = *(const float4*)(src + off);
    __bf16* o = out + i;
    o[0] = (__bf16)v.x; o[1] = (__bf16)v.y; o[2] = (__bf16)v.z; o[3] = (__bf16)v.w;
}

// ---------------------------------------------------------------------------
// Xc[r, 0:2048] = bf16(concat(emb_item[item_idx[r]], emb_skill[skill_idx[r]]))
// ---------------------------------------------------------------------------
__global__ __launch_bounds__(256) void embed_gather(
    const int* __restrict__ item_idx, const int* __restrict__ skill_idx,
    const float* __restrict__ emb_item, const float* __restrict__ emb_skill,
    __bf16* __restrict__ Xc) {
    const int r = blockIdx.x;
    const int c = threadIdx.x * 8;
    const float* s = (c < E_) ? emb_item + (size_t)item_idx[r] * E_ + c
                              : emb_skill + (size_t)skill_idx[r] * E_ + (c - E_);
    const float4 a = *(const float4*)s;
    const float4 b = *(const float4*)(s + 4);
    __bf16* o = Xc + (size_t)r * 2048 + c;
    o[0] = (__bf16)a.x; o[1] = (__bf16)a.y; o[2] = (__bf16)a.z; o[3] = (__bf16)a.w;
    o[4] = (__bf16)b.x; o[5] = (__bf16)b.y; o[6] = (__bf16)b.z; o[7] = (__bf16)b.w;
}

// ---------------------------------------------------------------------------
// Split-K stage 1: P[z][M_,1024] = A[M_,K]bf16 (K-half z) * Bm[1024,K]^T, f32.
// BM=128, BN=64, BK=64; grid (16, 32, 2) = 1024 blocks (4/CU).
// Round-10 single-buffer 2-barrier loop; 24 KB LDS.
// ---------------------------------------------------------------------------
__global__ __launch_bounds__(256) void gemm_ks(
    const __bf16* __restrict__ A, const __bf16* __restrict__ Bm,
    float* __restrict__ P, int K) {
    __shared__ __bf16 As[128 * 64];  // 16 KB
    __shared__ __bf16 Bs[64 * 64];   // 8 KB
    const int tid = threadIdx.x;
    const int lane = tid & 63;
    const int wid = tid >> 6;
    const int wm = wid >> 1;
    const int wn = wid & 1;
    const int l15 = lane & 15, lhi = lane >> 4;

    // XCD-chunked bijective swizzle over the FULL 3D grid (nwg = 1024)
    const int gx = gridDim.x;                        // 16
    const int per_z = gx * gridDim.y;                // 512
    const int id = (blockIdx.z * gridDim.y + blockIdx.y) * gx + blockIdx.x;
    const int nwg = per_z * 2;
    const int swz = (id & 7) * (nwg >> 3) + (id >> 3);
    const int z2 = swz / per_z;
    const int rem = swz - z2 * per_z;
    const int m0 = (rem / gx) * 128;
    const int n0 = (rem - (rem / gx) * gx) * 64;
    const int kbase = z2 * (K >> 1);

    const __bf16* pa[4];
    __bf16* la[4];
#pragma unroll
    for (int j = 0; j < 4; ++j) {
        const int ca = wid * 256 + j * 64 + lane;
        const int row = ca >> 3, ch = ca & 7;
        pa[j] = A + (size_t)(m0 + row) * K + ((ch ^ (row & 7)) << 3) + kbase;
        la[j] = As + (size_t)ca * 8;
    }
    const __bf16* pb[2];
    __bf16* lb[2];
#pragma unroll
    for (int j = 0; j < 2; ++j) {
        const int cb = wid * 128 + j * 64 + lane;
        const int row = cb >> 3, ch = cb & 7;
        pb[j] = Bm + (size_t)(n0 + row) * K + ((ch ^ (row & 7)) << 3) + kbase;
        lb[j] = Bs + (size_t)cb * 8;
    }

    int aoff[4][2], boff[2][2];
#pragma unroll
    for (int mi = 0; mi < 4; ++mi) {
        const int row = wm * 64 + mi * 16 + l15;
#pragma unroll
        for (int kc = 0; kc < 2; ++kc)
            aoff[mi][kc] = row * 64 + (((kc * 4 + lhi) ^ (row & 7)) << 3);
    }
#pragma unroll
    for (int ni = 0; ni < 2; ++ni) {
        const int row = wn * 32 + ni * 16 + l15;
#pragma unroll
        for (int kc = 0; kc < 2; ++kc)
            boff[ni][kc] = row * 64 + (((kc * 4 + lhi) ^ (row & 7)) << 3);
    }

    f32x4 acc[4][2] = {};
    const int KH = K >> 1;

    for (int k0 = 0; k0 < KH; k0 += 64) {
#pragma unroll
        for (int j = 0; j < 4; ++j)
            __builtin_amdgcn_global_load_lds(
                (const __attribute__((address_space(1))) unsigned int*)(pa[j] + k0),
                (__attribute__((address_space(3))) unsigned int*)la[j], 16, 0, 0);
#pragma unroll
        for (int j = 0; j < 2; ++j)
            __builtin_amdgcn_global_load_lds(
                (const __attribute__((address_space(1))) unsigned int*)(pb[j] + k0),
                (__attribute__((address_space(3))) unsigned int*)lb[j], 16, 0, 0);
        __syncthreads();
        bf16x8 af[4][2], bfr[2][2];
#pragma unroll
        for (int mi = 0; mi < 4; ++mi)
#pragma unroll
            for (int kc = 0; kc < 2; ++kc)
                af[mi][kc] = *(const bf16x8*)(As + aoff[mi][kc]);
#pragma unroll
        for (int ni = 0; ni < 2; ++ni)
#pragma unroll
            for (int kc = 0; kc < 2; ++kc)
                bfr[ni][kc] = *(const bf16x8*)(Bs + boff[ni][kc]);
#pragma unroll
        for (int mi = 0; mi < 4; ++mi)
#pragma unroll
            for (int ni = 0; ni < 2; ++ni)
#pragma unroll
                for (int kc = 0; kc < 2; ++kc)
                    acc[mi][ni] = __builtin_amdgcn_mfma_f32_16x16x32_bf16(
                        af[mi][kc], bfr[ni][kc], acc[mi][ni], 0, 0, 0);
        __syncthreads();
    }

    float* Pz = P + (size_t)z2 * M_ * E_;
    const int ccol0 = n0 + wn * 32 + l15;
    const int crow0 = m0 + wm * 64 + (lhi << 2);
#pragma unroll
    for (int mi = 0; mi < 4; ++mi)
#pragma unroll
        for (int ni = 0; ni < 2; ++ni) {
            const int col = ccol0 + ni * 16;
#pragma unroll
            for (int r = 0; r < 4; ++r)
                Pz[(size_t)(crow0 + mi * 16 + r) * E_ + col] = acc[mi][ni][r];
        }
}

// ---------------------------------------------------------------------------
// Split-K epilogue: C[i] = f(P0[i] + P1[i] + bias[col]) as bf16, row-major.
// ---------------------------------------------------------------------------
template <int ACT>
__global__ __launch_bounds__(256) void ep_sum(
    const float* __restrict__ P, const float* __restrict__ bias,
    __bf16* __restrict__ C) {
    const size_t idx = ((size_t)blockIdx.x * 256 + threadIdx.x) * 8;  // < 4M
    const int col = (int)(idx & (E_ - 1));
    const float4 a0 = *(const float4*)(P + idx);
    const float4 a1 = *(const float4*)(P + idx + 4);
    const float4 b0 = *(const float4*)(P + (size_t)M_ * E_ + idx);
    const float4 b1 = *(const float4*)(P + (size_t)M_ * E_ + idx + 4);
    const float4 s0 = *(const float4*)(bias + col);
    const float4 s1 = *(const float4*)(bias + col + 4);
    float v[8] = {a0.x + b0.x + s0.x, a0.y + b0.y + s0.y,
                  a0.z + b0.z + s0.z, a0.w + b0.w + s0.w,
                  a1.x + b1.x + s1.x, a1.y + b1.y + s1.y,
                  a1.z + b1.z + s1.z, a1.w + b1.w + s1.w};
    bf16x8 o;
#pragma unroll
    for (int j = 0; j < 8; ++j) o[j] = (__bf16)(ACT ? gelu_exact(v[j]) : v[j]);
    *(bf16x8*)(C + idx) = o;
}

// ---------------------------------------------------------------------------
// Direct kv GEMM (N=2048): C = Qb * [Wk;Wv]^T; K-pack + pe for cols<1024,
// V-pack + bias2 for cols>=1024. Round-10 single-buffer 2-barrier loop.
// ---------------------------------------------------------------------------
__global__ __launch_bounds__(256) void gemm_kv(
    const __bf16* __restrict__ A, const __bf16* __restrict__ Bm,
    const float* __restrict__ bias, __bf16* __restrict__ C, int K,
    const float* __restrict__ pe, const float* __restrict__ bias2) {
    __shared__ __bf16 As[128 * 64];
    __shared__ __bf16 Bs[64 * 64];
    const int tid = threadIdx.x;
    const int lane = tid & 63;
    const int wid = tid >> 6;
    const int wm = wid >> 1;
    const int wn = wid & 1;
    const int l15 = lane & 15, lhi = lane >> 4;

    const int gx = gridDim.x;
    const int id = blockIdx.y * gx + blockIdx.x;
    const int nwg = gx * gridDim.y;
    const int swz = (id & 7) * (nwg >> 3) + (id >> 3);
    const int m0 = (swz / gx) * 128;
    const int n0 = (swz % gx) * 64;

    const __bf16* pa[4];
    __bf16* la[4];
#pragma unroll
    for (int j = 0; j < 4; ++j) {
        const int ca = wid * 256 + j * 64 + lane;
        const int row = ca >> 3, ch = ca & 7;
        pa[j] = A + (size_t)(m0 + row) * K + ((ch ^ (row & 7)) << 3);
        la[j] = As + (size_t)ca * 8;
    }
    const __bf16* pb[2];
    __bf16* lb[2];
#pragma unroll
    for (int j = 0; j < 2; ++j) {
        const int cb = wid * 128 + j * 64 + lane;
        const int row = cb >> 3, ch = cb & 7;
        pb[j] = Bm + (size_t)(n0 + row) * K + ((ch ^ (row & 7)) << 3);
        lb[j] = Bs + (size_t)cb * 8;
    }

    int aoff[4][2], boff[2][2];
#pragma unroll
    for (int mi = 0; mi < 4; ++mi) {
        const int row = wm * 64 + mi * 16 + l15;
#pragma unroll
        for (int kc = 0; kc < 2; ++kc)
            aoff[mi][kc] = row * 64 + (((kc * 4 + lhi) ^ (row & 7)) << 3);
    }
#pragma unroll
    for (int ni = 0; ni < 2; ++ni) {
        const int row = wn * 32 + ni * 16 + l15;
#pragma unroll
        for (int kc = 0; kc < 2; ++kc)
            boff[ni][kc] = row * 64 + (((kc * 4 + lhi) ^ (row & 7)) << 3);
    }

    f32x4 acc[4][2] = {};

    for (int k0 = 0; k0 < K; k0 += 64) {
#pragma unroll
        for (int j = 0; j < 4; ++j)
            __builtin_amdgcn_global_load_lds(
                (const __attribute__((address_space(1))) unsigned int*)(pa[j] + k0),
                (__attribute__((address_space(3))) unsigned int*)la[j], 16, 0, 0);
#pragma unroll
        for (int j = 0; j < 2; ++j)
            __builtin_amdgcn_global_load_lds(
                (const __attribute__((address_space(1))) unsigned int*)(pb[j] + k0),
                (__attribute__((address_space(3))) unsigned int*)lb[j], 16, 0, 0);
        __syncthreads();
        bf16x8 af[4][2], bfr[2][2];
#pragma unroll
        for (int mi = 0; mi < 4; ++mi)
#pragma unroll
            for (int kc = 0; kc < 2; ++kc)
                af[mi][kc] = *(const bf16x8*)(As + aoff[mi][kc]);
#pragma unroll
        for (int ni = 0; ni < 2; ++ni)
#pragma unroll
            for (int kc = 0; kc < 2; ++kc)
                bfr[ni][kc] = *(const bf16x8*)(Bs + boff[ni][kc]);
#pragma unroll
        for (int mi = 0; mi < 4; ++mi)
#pragma unroll
            for (int ni = 0; ni < 2; ++ni)
#pragma unroll
                for (int kc = 0; kc < 2; ++kc)
                    acc[mi][ni] = __builtin_amdgcn_mfma_f32_16x16x32_bf16(
                        af[mi][kc], bfr[ni][kc], acc[mi][ni], 0, 0, 0);
        __syncthreads();
    }

    const int ccol0 = n0 + wn * 32 + l15;
    const int crow0 = m0 + wm * 64 + (lhi << 2);
#pragma unroll
    for (int mi = 0; mi < 4; ++mi) {
#pragma unroll
        for (int ni = 0; ni < 2; ++ni) {
            const int col = ccol0 + ni * 16;
            const float bsum = (col < 1024) ? bias[col] : bias2[col - 1024];
#pragma unroll
            for (int r = 0; r < 4; ++r) {
                const int row = crow0 + mi * 16 + r;
                float v = acc[mi][ni][r] + bsum;
                if (col < 1024) {
                    v += pe[((row & (S_ - 1)) << 6) + (col & (D_ - 1))];
                    C[kpack_idx(row, col)] = (__bf16)v;
                } else {
                    C[(size_t)M_ * E_ + vpack_idx(row, col - 1024)] = (__bf16)v;
                }
            }
        }
    }
}

// ---------------------------------------------------------------------------
// Swapped-QK MFMA flash attention, LDS-staged K/V shared by 8 waves.
// ---------------------------------------------------------------------------
__global__ __launch_bounds__(512) void attn_mfma(
    const __bf16* __restrict__ Q, const __bf16* __restrict__ Kp,
    const __bf16* __restrict__ Vp, __bf16* __restrict__ O) {
    __shared__ __bf16 Slds[2][2][8 * 512];  // 32 KB
    const int tid = threadIdx.x;
    const int lane = tid & 63;
    const int w = tid >> 6;
    const int l15 = lane & 15, lhi = lane >> 4;

    const int id = blockIdx.y * gridDim.x + blockIdx.x;  // 0..511
    const int swz = (id & 7) * 64 + (id >> 3);
    const int q0 = (swz & 7) * 128 + w * 16;
    const int bh = swz >> 3;
    const int bb = bh >> 4, hh = bh & 15;

    bf16x8 qf[2];
    {
        const __bf16* qrow =
            Q + (size_t)(bb * S_ + q0 + l15) * E_ + hh * 64 + lhi * 8;
#pragma unroll
        for (int kc = 0; kc < 2; ++kc) {
            const u16x8 raw = *(const u16x8*)(qrow + kc * 32);
            bf16x8 v;
#pragma unroll
            for (int j = 0; j < 8; ++j) v[j] = (__bf16)(bf2f(raw[j]) * 0.125f);
            qf[kc] = v;
        }
    }

    const __bf16* kpw = Kp + ((size_t)bh * 16 * 8 + w) * 512 + lane * 8;
    const __bf16* vpw = Vp + ((size_t)bh * 16 * 8 + w) * 512 + lane * 8;

    float m_l = -1e30f, l_l = 0.f;
    f32x4 oacc[4] = {};

    __builtin_amdgcn_global_load_lds(
        (const __attribute__((address_space(1))) unsigned int*)(kpw),
        (__attribute__((address_space(3))) unsigned int*)(&Slds[0][0][w * 512]),
        16, 0, 0);
    __builtin_amdgcn_global_load_lds(
        (const __attribute__((address_space(1))) unsigned int*)(vpw),
        (__attribute__((address_space(3))) unsigned int*)(&Slds[0][1][w * 512]),
        16, 0, 0);

#pragma unroll 2
    for (int kt = 0; kt < S_ / 64; ++kt) {
        const int cur = kt & 1;
        __syncthreads();
        if (kt < S_ / 64 - 1) {
            const size_t fo = (size_t)(kt + 1) * 8 * 512;
            __builtin_amdgcn_global_load_lds(
                (const __attribute__((address_space(1))) unsigned int*)(kpw + fo),
                (__attribute__((address_space(3))) unsigned int*)(
                    &Slds[cur ^ 1][0][w * 512]), 16, 0, 0);
            __builtin_amdgcn_global_load_lds(
                (const __attribute__((address_space(1))) unsigned int*)(vpw + fo),
                (__attribute__((address_space(3))) unsigned int*)(
                    &Slds[cur ^ 1][1][w * 512]), 16, 0, 0);
        }
        const __bf16* kl = &Slds[cur][0][0];
        const __bf16* vl = &Slds[cur][1][0];
        f32x4 s[4];
#pragma unroll
        for (int kb = 0; kb < 4; ++kb) {
            const bf16x8 k0 = *(const bf16x8*)(kl + (kb * 2 + 0) * 512 + lane * 8);
            const bf16x8 k1 = *(const bf16x8*)(kl + (kb * 2 + 1) * 512 + lane * 8);
            f32x4 z = {};
            z = __builtin_amdgcn_mfma_f32_16x16x32_bf16(k0, qf[0], z, 0, 0, 0);
            s[kb] = __builtin_amdgcn_mfma_f32_16x16x32_bf16(k1, qf[1], z, 0, 0, 0);
        }
        float mx0 = fmaxf(fmaxf(s[0][0], s[0][1]), fmaxf(s[0][2], s[0][3]));
        float mx1 = fmaxf(fmaxf(s[1][0], s[1][1]), fmaxf(s[1][2], s[1][3]));
        float mx2 = fmaxf(fmaxf(s[2][0], s[2][1]), fmaxf(s[2][2], s[2][3]));
        float mx3 = fmaxf(fmaxf(s[3][0], s[3][1]), fmaxf(s[3][2], s[3][3]));
        float mx = fmaxf(fmaxf(mx0, mx1), fmaxf(mx2, mx3));
        mx = fmaxf(mx, __shfl_xor(mx, 16));
        mx = fmaxf(mx, __shfl_xor(mx, 32));
        const float mnew = fmaxf(m_l, mx);
        const float corr = __expf(m_l - mnew);
        float p[4][4];
        float rs = 0.f;
#pragma unroll
        for (int kb = 0; kb < 4; ++kb) {
            float sb = 0.f;
#pragma unroll
            for (int r = 0; r < 4; ++r) {
                p[kb][r] = __expf(s[kb][r] - mnew);
                sb += p[kb][r];
            }
            rs += sb;
        }
        rs += __shfl_xor(rs, 16);
        rs += __shfl_xor(rs, 32);
        l_l = l_l * corr + rs;
        m_l = mnew;
#pragma unroll
        for (int db = 0; db < 4; ++db)
#pragma unroll
            for (int r = 0; r < 4; ++r) oacc[db][r] *= corr;
        bf16x8 pf[2];
#pragma unroll
        for (int kc = 0; kc < 2; ++kc) {
            bf16x8 v;
#pragma unroll
            for (int r = 0; r < 4; ++r) {
                v[r] = (__bf16)p[kc * 2][r];
                v[r + 4] = (__bf16)p[kc * 2 + 1][r];
            }
            pf[kc] = v;
        }
#pragma unroll
        for (int db = 0; db < 4; ++db) {
            const bf16x8 v0 = *(const bf16x8*)(vl + (db * 2 + 0) * 512 + lane * 8);
            const bf16x8 v1 = *(const bf16x8*)(vl + (db * 2 + 1) * 512 + lane * 8);
            oacc[db] = __builtin_amdgcn_mfma_f32_16x16x32_bf16(v0, pf[0], oacc[db], 0, 0, 0);
            oacc[db] = __builtin_amdgcn_mfma_f32_16x16x32_bf16(v1, pf[1], oacc[db], 0, 0, 0);
        }
    }
    const float inv_l = 1.f / l_l;
    __bf16* orow = O + (size_t)(bb * S_ + q0 + l15) * E_ + hh * 64 + lhi * 4;
#pragma unroll
    for (int db = 0; db < 4; ++db) {
        bf16x4 ov;
#pragma unroll
        for (int r = 0; r < 4; ++r) ov[r] = (__bf16)(oacc[db][r] * inv_l);
        *(bf16x4*)(orow + db * 16) = ov;
    }
}

// ---------------------------------------------------------------------------
// out[m] = bf16 x[m,:] . f32 W_out + b_out -> f32. One wave per row.
// ---------------------------------------------------------------------------
__global__ __launch_bounds__(256) void final_proj(
    const __bf16* __restrict__ X, const float* __restrict__ Wout,
    const float* __restrict__ bout, float* __restrict__ out) {
    const int wid = threadIdx.x >> 6, lane = threadIdx.x & 63;
    const int m = blockIdx.x * 4 + wid;
    const __bf16* xrow = X + (size_t)m * E_;
    float acc = 0.f;
#pragma unroll
    for (int c = 0; c < 2; ++c) {
        const int idx = c * 512 + lane * 8;
        const u16x8 xv = *(const u16x8*)(xrow + idx);
        const float4 w1 = *(const float4*)(Wout + idx);
        const float4 w2 = *(const float4*)(Wout + idx + 4);
        acc += bf2f(xv[0]) * w1.x + bf2f(xv[1]) * w1.y + bf2f(xv[2]) * w1.z +
               bf2f(xv[3]) * w1.w + bf2f(xv[4]) * w2.x + bf2f(xv[5]) * w2.y +
               bf2f(xv[6]) * w2.z + bf2f(xv[7]) * w2.w;
    }
#pragma unroll
    for (int off = 32; off; off >>= 1) acc += __shfl_xor(acc, off, 64);
    if (lane == 0) out[m] = acc + bout[0];
}

extern "C" void kernel_launch(void* const* d_in, const int* in_sizes, int n_in,
                              void* d_out, int out_size, void* d_ws, size_t ws_size,
                              hipStream_t stream) {
    const int* item_inputs = (const int*)d_in[0];
    const int* skill_inputs = (const int*)d_in[1];
    const float* emb_item = (const float*)d_in[5];
    const float* emb_skill = (const float*)d_in[6];
    const float* W_in = (const float*)d_in[7];
    const float* b_in = (const float*)d_in[8];
    const float* Wq = (const float*)d_in[9];
    const float* bq = (const float*)d_in[10];
    const float* Wk = (const float*)d_in[11];
    const float* bk = (const float*)d_in[12];
    const float* Wv = (const float*)d_in[13];
    const float* bv = (const float*)d_in[14];
    // d_in[15] Wg, d_in[16] bg: softmax-invariant, skipped.
    const float* pos_key = (const float*)d_in[17];
    const float* Wl = (const float*)d_in[18];
    const float* bl = (const float*)d_in[19];
    const float* W_out = (const float*)d_in[20];
    const float* b_out = (const float*)d_in[21];
    float* out = (float*)d_out;

    const size_t SZ = (size_t)M_ * E_;  // 4M
    __bf16* Xc = (__bf16*)d_ws;         // 8M elems
    __bf16* X = Xc + (size_t)M_ * 2048;
    __bf16* Qb = X + SZ;
    __bf16* Kp = Qb + SZ;               // packed K fragments / MLP scratch
    __bf16* Vp = Kp + SZ;               // packed V fragments
    __bf16* Winb = Vp + SZ;             // 2M elems
    __bf16* Wall = Winb + 2 * EE;       // 24M elems
    float* Pbuf = (float*)(Wall + (size_t)L_ * 6 * EE);  // 8M f32 = 32 MB

    const dim3 ggks(16, 32, 2);          // split-K: 1024 blocks
    const dim3 ggkv(32, 32);             // kv direct: 1024 blocks
    const dim3 gge(2048);                // epilogue: 4M/8/256
    const dim3 bb(256);

    embed_gather<<<dim3(M_), bb, 0, stream>>>(item_inputs, skill_inputs,
                                              emb_item, emb_skill, Xc);
    cvt_f32_bf16<<<dim3(2 * EE / 1024), bb, 0, stream>>>(W_in, Winb, 2 * EE);
    cvt_all_weights<<<dim3(L_ * 6 * EE / 1024), bb, 0, stream>>>(Wq, Wk, Wv, Wl, Wall);

    gemm_ks<<<ggks, bb, 0, stream>>>(Xc, Winb, Pbuf, 2048);
    ep_sum<0><<<gge, bb, 0, stream>>>(Pbuf, b_in, X);

    for (int l = 0; l < L_; ++l) {
        __bf16* Wbuf = Wall + (size_t)l * 6 * EE;
        const float* pe_l = pos_key + (size_t)l * S_ * D_;
        gemm_ks<<<ggks, bb, 0, stream>>>(X, Wbuf + 0 * EE, Pbuf, E_);
        ep_sum<0><<<gge, bb, 0, stream>>>(Pbuf, bq + l * E_, Qb);
        gemm_kv<<<ggkv, bb, 0, stream>>>(Qb, Wbuf + 1 * EE, bk + l * E_, Kp, E_,
                                         pe_l, bv + l * E_);
        attn_mfma<<<dim3(S_ / 128, B_ * H_), dim3(512), 0, stream>>>(Qb, Kp, Vp, X);
        gemm_ks<<<ggks, bb, 0, stream>>>(X, Wbuf + 3 * EE, Pbuf, E_);
        ep_sum<1><<<gge, bb, 0, stream>>>(Pbuf, bl + (l * 3 + 0) * E_, Qb);
        gemm_ks<<<ggks, bb, 0, stream>>>(Qb, Wbuf + 4 * EE, Pbuf, E_);
        ep_sum<1><<<gge, bb, 0, stream>>>(Pbuf, bl + (l * 3 + 1) * E_, Kp);
        gemm_ks<<<ggks, bb, 0, stream>>>(Kp, Wbuf + 5 * EE, Pbuf, E_);
        ep_sum<1><<<gge, bb, 0, stream>>>(Pbuf, bl + (l * 3 + 2) * E_, X);
    }
    final_proj<<<dim3(M_ / 4), bb, 0, stream>>>(X, W_out, b_out, out);
}

// Round 14
// 544.219 us; speedup vs baseline: 1.2756x; 1.2756x over previous
//
#include <hip/hip_runtime.h>
#include <hip/hip_bf16.h>

// AKT forward, round 14: revert split-K; all N=1024 GEMMs -> 64x64 tiles
// (grid 1024 blocks = 4/CU, same total traffic) with the proven r10
// single-buffer 2-barrier K-loop. kv-GEMM (128x64, 4/CU) and attn unchanged.
// cvt kernels vectorized to 8 elems/thread (16B stores).
//   - glo term dropped (softmax-invariant per-query constant)
//   - pos_key folded into kv-GEMM epilogue
// Workspace (~100 MB): Xc 8M | X,Qb,Kp,Vp 4M | Winb 2M | Wall 24M elems

#define B_ 4
#define S_ 1024
#define E_ 1024
#define H_ 16
#define D_ 64
#define L_ 4
#define M_ (B_ * S_)  // 4096
#define EE (E_ * E_)  // 1M

typedef __attribute__((ext_vector_type(8))) __bf16 bf16x8;
typedef __attribute__((ext_vector_type(4))) __bf16 bf16x4;
typedef __attribute__((ext_vector_type(4))) float f32x4;
typedef __attribute__((ext_vector_type(8))) unsigned short u16x8;

__device__ __forceinline__ float bf2f(unsigned short u) {
    union { unsigned int i; float f; } x;
    x.i = ((unsigned int)u) << 16;
    return x.f;
}
__device__ __forceinline__ float gelu_exact(float x) {
    return 0.5f * x * (1.0f + erff(x * 0.70710678118654752f));
}

// Packed K layout: frag=((bh*16+kt)*4+kb)*2+kc, elem=lane*8+j.
__device__ __forceinline__ size_t kpack_idx(int m, int col) {
    const int b = m >> 10, srow = m & (S_ - 1);
    const int h = col >> 6, d = col & 63;
    const int bh = b * H_ + h;
    const int kt = srow >> 6, kb = (srow >> 4) & 3, l15 = srow & 15;
    const int kc = d >> 5, lhi = (d >> 3) & 3, j = d & 7;
    const int frag = ((bh * 16 + kt) * 4 + kb) * 2 + kc;
    return (size_t)frag * 512 + (size_t)(lhi * 16 + l15) * 8 + j;
}
// Packed V layout (key-permuted to match P^T B-fragments).
__device__ __forceinline__ size_t vpack_idx(int m, int col) {
    const int b = m >> 10, key = m & (S_ - 1);
    const int h = col >> 6, d = col & 63;
    const int bh = b * H_ + h;
    const int kt = key >> 6;
    const int k6 = key & 63;
    const int kc = k6 >> 5, kl = k6 & 31;
    const int lhi = (kl >> 2) & 3;
    const int j = ((kl >> 4) << 2) | (kl & 3);
    const int db = d >> 4, l15 = d & 15;
    const int frag = ((bh * 16 + kt) * 4 + db) * 2 + kc;
    return (size_t)frag * 512 + (size_t)(lhi * 16 + l15) * 8 + j;
}

// ---------------------------------------------------------------------------
// f32 -> bf16 bulk convert, 8 elems/thread, 16B store.
// ---------------------------------------------------------------------------
__global__ __launch_bounds__(256) void cvt_f32_bf16(
    const float* __restrict__ in, __bf16* __restrict__ out, int n) {
    const int i = (blockIdx.x * 256 + threadIdx.x) * 8;
    if (i >= n) return;
    const float4 a = *(const float4*)(in + i);
    const float4 b = *(const float4*)(in + i + 4);
    bf16x8 o;
    o[0] = (__bf16)a.x; o[1] = (__bf16)a.y; o[2] = (__bf16)a.z; o[3] = (__bf16)a.w;
    o[4] = (__bf16)b.x; o[5] = (__bf16)b.y; o[6] = (__bf16)b.z; o[7] = (__bf16)b.w;
    *(bf16x8*)(out + i) = o;
}

// ALL layers: Wq,Wk,Wv,Wl (L_ layers, 6 matrices each) -> Wall[24M] bf16
__global__ __launch_bounds__(256) void cvt_all_weights(
    const float* __restrict__ Wq, const float* __restrict__ Wk,
    const float* __restrict__ Wv, const float* __restrict__ Wl,
    __bf16* __restrict__ out) {
    const int i = (blockIdx.x * 256 + threadIdx.x) * 8;  // < 24M
    const int l = i / (6 * EE);
    const int r = i - l * 6 * EE;
    const int mat = r >> 20;
    const int off = r & (EE - 1);
    const float* src = (mat == 0) ? Wq + (size_t)l * EE
                     : (mat == 1) ? Wk + (size_t)l * EE
                     : (mat == 2) ? Wv + (size_t)l * EE
                                  : Wl + ((size_t)l * 3 + (mat - 3)) * EE;
    const float4 a = *(const float4*)(src + off);
    const float4 b = *(const float4*)(src + off + 4);
    bf16x8 o;
    o[0] = (__bf16)a.x; o[1] = (__bf16)a.y; o[2] = (__bf16)a.z; o[3] = (__bf16)a.w;
    o[4] = (__bf16)b.x; o[5] = (__bf16)b.y; o[6] = (__bf16)b.z; o[7] = (__bf16)b.w;
    *(bf16x8*)(out + i) = o;
}

// ---------------------------------------------------------------------------
// Xc[r, 0:2048] = bf16(concat(emb_item[item_idx[r]], emb_skill[skill_idx[r]]))
// ---------------------------------------------------------------------------
__global__ __launch_bounds__(256) void embed_gather(
    const int* __restrict__ item_idx, const int* __restrict__ skill_idx,
    const float* __restrict__ emb_item, const float* __restrict__ emb_skill,
    __bf16* __restrict__ Xc) {
    const int r = blockIdx.x;
    const int c = threadIdx.x * 8;
    const float* s = (c < E_) ? emb_item + (size_t)item_idx[r] * E_ + c
                              : emb_skill + (size_t)skill_idx[r] * E_ + (c - E_);
    const float4 a = *(const float4*)s;
    const float4 b = *(const float4*)(s + 4);
    bf16x8 o;
    o[0] = (__bf16)a.x; o[1] = (__bf16)a.y; o[2] = (__bf16)a.z; o[3] = (__bf16)a.w;
    o[4] = (__bf16)b.x; o[5] = (__bf16)b.y; o[6] = (__bf16)b.z; o[7] = (__bf16)b.w;
    *(bf16x8*)(Xc + (size_t)r * 2048 + c) = o;
}

// ---------------------------------------------------------------------------
// 64x64-tile GEMM: C[M_,1024]bf16 = A[M_,K] * Bm[1024,K]^T + bias; opt GELU.
// BM=BN=64, BK=64; 256 threads = 4 waves (2x2), wave tile 32x32 (8 MFMA/step).
// Grid (16, 64) = 1024 blocks = 4/CU. Single-buffer 2-barrier loop (r10).
// Swizzle chunk' = ch ^ (row&7) both sides. XCD-chunked block swizzle.
// ---------------------------------------------------------------------------
template <int ACT>
__global__ __launch_bounds__(256) void gemm64(
    const __bf16* __restrict__ A, const __bf16* __restrict__ Bm,
    const float* __restrict__ bias, __bf16* __restrict__ C, int K) {
    __shared__ __bf16 As[64 * 64];  // 8 KB
    __shared__ __bf16 Bs[64 * 64];  // 8 KB
    const int tid = threadIdx.x;
    const int lane = tid & 63;
    const int wid = tid >> 6;
    const int wm = wid >> 1;
    const int wn = wid & 1;
    const int l15 = lane & 15, lhi = lane >> 4;

    // XCD-chunked bijective swizzle (nwg = 1024)
    const int gx = gridDim.x;  // 16
    const int id = blockIdx.y * gx + blockIdx.x;
    const int nwg = gx * gridDim.y;
    const int swz = (id & 7) * (nwg >> 3) + (id >> 3);
    const int m0 = (swz / gx) * 64;
    const int n0 = (swz % gx) * 64;

    // staging: A,B each 512 chunks of 16B -> 2/thread each.
    const __bf16* pa[2];
    __bf16* la[2];
    const __bf16* pb[2];
    __bf16* lb[2];
#pragma unroll
    for (int j = 0; j < 2; ++j) {
        const int c = wid * 128 + j * 64 + lane;
        const int row = c >> 3, ch = c & 7;
        pa[j] = A + (size_t)(m0 + row) * K + ((ch ^ (row & 7)) << 3);
        la[j] = As + (size_t)c * 8;
        pb[j] = Bm + (size_t)(n0 + row) * K + ((ch ^ (row & 7)) << 3);
        lb[j] = Bs + (size_t)c * 8;
    }

    // ds_read offsets: row*64 + ((kc*4+lhi)^(row&7))*8
    int aoff[2][2], boff[2][2];
#pragma unroll
    for (int mi = 0; mi < 2; ++mi) {
        const int row = wm * 32 + mi * 16 + l15;
#pragma unroll
        for (int kc = 0; kc < 2; ++kc)
            aoff[mi][kc] = row * 64 + (((kc * 4 + lhi) ^ (row & 7)) << 3);
    }
#pragma unroll
    for (int ni = 0; ni < 2; ++ni) {
        const int row = wn * 32 + ni * 16 + l15;
#pragma unroll
        for (int kc = 0; kc < 2; ++kc)
            boff[ni][kc] = row * 64 + (((kc * 4 + lhi) ^ (row & 7)) << 3);
    }

    f32x4 acc[2][2] = {};

    for (int k0 = 0; k0 < K; k0 += 64) {
#pragma unroll
        for (int j = 0; j < 2; ++j) {
            __builtin_amdgcn_global_load_lds(
                (const __attribute__((address_space(1))) unsigned int*)(pa[j] + k0),
                (__attribute__((address_space(3))) unsigned int*)la[j], 16, 0, 0);
            __builtin_amdgcn_global_load_lds(
                (const __attribute__((address_space(1))) unsigned int*)(pb[j] + k0),
                (__attribute__((address_space(3))) unsigned int*)lb[j], 16, 0, 0);
        }
        __syncthreads();
        bf16x8 af[2][2], bfr[2][2];
#pragma unroll
        for (int mi = 0; mi < 2; ++mi)
#pragma unroll
            for (int kc = 0; kc < 2; ++kc)
                af[mi][kc] = *(const bf16x8*)(As + aoff[mi][kc]);
#pragma unroll
        for (int ni = 0; ni < 2; ++ni)
#pragma unroll
            for (int kc = 0; kc < 2; ++kc)
                bfr[ni][kc] = *(const bf16x8*)(Bs + boff[ni][kc]);
#pragma unroll
        for (int mi = 0; mi < 2; ++mi)
#pragma unroll
            for (int ni = 0; ni < 2; ++ni)
#pragma unroll
                for (int kc = 0; kc < 2; ++kc)
                    acc[mi][ni] = __builtin_amdgcn_mfma_f32_16x16x32_bf16(
                        af[mi][kc], bfr[ni][kc], acc[mi][ni], 0, 0, 0);
        __syncthreads();
    }

    const int ccol0 = n0 + wn * 32 + l15;
    const int crow0 = m0 + wm * 32 + (lhi << 2);
#pragma unroll
    for (int mi = 0; mi < 2; ++mi) {
#pragma unroll
        for (int ni = 0; ni < 2; ++ni) {
            const int col = ccol0 + ni * 16;
            const float bsum = bias[col];
#pragma unroll
            for (int r = 0; r < 4; ++r) {
                const int row = crow0 + mi * 16 + r;
                float v = acc[mi][ni][r] + bsum;
                if (ACT) v = gelu_exact(v);
                C[(size_t)row * E_ + col] = (__bf16)v;
            }
        }
    }
}

// ---------------------------------------------------------------------------
// Direct kv GEMM (N=2048): C = Qb * [Wk;Wv]^T; K-pack + pe for cols<1024,
// V-pack + bias2 for cols>=1024. BM=128,BN=64,BK=64 single-buffer loop.
// ---------------------------------------------------------------------------
__global__ __launch_bounds__(256) void gemm_kv(
    const __bf16* __restrict__ A, const __bf16* __restrict__ Bm,
    const float* __restrict__ bias, __bf16* __restrict__ C, int K,
    const float* __restrict__ pe, const float* __restrict__ bias2) {
    __shared__ __bf16 As[128 * 64];
    __shared__ __bf16 Bs[64 * 64];
    const int tid = threadIdx.x;
    const int lane = tid & 63;
    const int wid = tid >> 6;
    const int wm = wid >> 1;
    const int wn = wid & 1;
    const int l15 = lane & 15, lhi = lane >> 4;

    const int gx = gridDim.x;
    const int id = blockIdx.y * gx + blockIdx.x;
    const int nwg = gx * gridDim.y;
    const int swz = (id & 7) * (nwg >> 3) + (id >> 3);
    const int m0 = (swz / gx) * 128;
    const int n0 = (swz % gx) * 64;

    const __bf16* pa[4];
    __bf16* la[4];
#pragma unroll
    for (int j = 0; j < 4; ++j) {
        const int ca = wid * 256 + j * 64 + lane;
        const int row = ca >> 3, ch = ca & 7;
        pa[j] = A + (size_t)(m0 + row) * K + ((ch ^ (row & 7)) << 3);
        la[j] = As + (size_t)ca * 8;
    }
    const __bf16* pb[2];
    __bf16* lb[2];
#pragma unroll
    for (int j = 0; j < 2; ++j) {
        const int cb = wid * 128 + j * 64 + lane;
        const int row = cb >> 3, ch = cb & 7;
        pb[j] = Bm + (size_t)(n0 + row) * K + ((ch ^ (row & 7)) << 3);
        lb[j] = Bs + (size_t)cb * 8;
    }

    int aoff[4][2], boff[2][2];
#pragma unroll
    for (int mi = 0; mi < 4; ++mi) {
        const int row = wm * 64 + mi * 16 + l15;
#pragma unroll
        for (int kc = 0; kc < 2; ++kc)
            aoff[mi][kc] = row * 64 + (((kc * 4 + lhi) ^ (row & 7)) << 3);
    }
#pragma unroll
    for (int ni = 0; ni < 2; ++ni) {
        const int row = wn * 32 + ni * 16 + l15;
#pragma unroll
        for (int kc = 0; kc < 2; ++kc)
            boff[ni][kc] = row * 64 + (((kc * 4 + lhi) ^ (row & 7)) << 3);
    }

    f32x4 acc[4][2] = {};

    for (int k0 = 0; k0 < K; k0 += 64) {
#pragma unroll
        for (int j = 0; j < 4; ++j)
            __builtin_amdgcn_global_load_lds(
                (const __attribute__((address_space(1))) unsigned int*)(pa[j] + k0),
                (__attribute__((address_space(3))) unsigned int*)la[j], 16, 0, 0);
#pragma unroll
        for (int j = 0; j < 2; ++j)
            __builtin_amdgcn_global_load_lds(
                (const __attribute__((address_space(1))) unsigned int*)(pb[j] + k0),
                (__attribute__((address_space(3))) unsigned int*)lb[j], 16, 0, 0);
        __syncthreads();
        bf16x8 af[4][2], bfr[2][2];
#pragma unroll
        for (int mi = 0; mi < 4; ++mi)
#pragma unroll
            for (int kc = 0; kc < 2; ++kc)
                af[mi][kc] = *(const bf16x8*)(As + aoff[mi][kc]);
#pragma unroll
        for (int ni = 0; ni < 2; ++ni)
#pragma unroll
            for (int kc = 0; kc < 2; ++kc)
                bfr[ni][kc] = *(const bf16x8*)(Bs + boff[ni][kc]);
#pragma unroll
        for (int mi = 0; mi < 4; ++mi)
#pragma unroll
            for (int ni = 0; ni < 2; ++ni)
#pragma unroll
                for (int kc = 0; kc < 2; ++kc)
                    acc[mi][ni] = __builtin_amdgcn_mfma_f32_16x16x32_bf16(
                        af[mi][kc], bfr[ni][kc], acc[mi][ni], 0, 0, 0);
        __syncthreads();
    }

    const int ccol0 = n0 + wn * 32 + l15;
    const int crow0 = m0 + wm * 64 + (lhi << 2);
#pragma unroll
    for (int mi = 0; mi < 4; ++mi) {
#pragma unroll
        for (int ni = 0; ni < 2; ++ni) {
            const int col = ccol0 + ni * 16;
            const float bsum = (col < 1024) ? bias[col] : bias2[col - 1024];
#pragma unroll
            for (int r = 0; r < 4; ++r) {
                const int row = crow0 + mi * 16 + r;
                float v = acc[mi][ni][r] + bsum;
                if (col < 1024) {
                    v += pe[((row & (S_ - 1)) << 6) + (col & (D_ - 1))];
                    C[kpack_idx(row, col)] = (__bf16)v;
                } else {
                    C[(size_t)M_ * E_ + vpack_idx(row, col - 1024)] = (__bf16)v;
                }
            }
        }
    }
}

// ---------------------------------------------------------------------------
// Swapped-QK MFMA flash attention, LDS-staged K/V shared by 8 waves.
// ---------------------------------------------------------------------------
__global__ __launch_bounds__(512) void attn_mfma(
    const __bf16* __restrict__ Q, const __bf16* __restrict__ Kp,
    const __bf16* __restrict__ Vp, __bf16* __restrict__ O) {
    __shared__ __bf16 Slds[2][2][8 * 512];  // 32 KB
    const int tid = threadIdx.x;
    const int lane = tid & 63;
    const int w = tid >> 6;
    const int l15 = lane & 15, lhi = lane >> 4;

    const int id = blockIdx.y * gridDim.x + blockIdx.x;  // 0..511
    const int swz = (id & 7) * 64 + (id >> 3);
    const int q0 = (swz & 7) * 128 + w * 16;
    const int bh = swz >> 3;
    const int bb = bh >> 4, hh = bh & 15;

    bf16x8 qf[2];
    {
        const __bf16* qrow =
            Q + (size_t)(bb * S_ + q0 + l15) * E_ + hh * 64 + lhi * 8;
#pragma unroll
        for (int kc = 0; kc < 2; ++kc) {
            const u16x8 raw = *(const u16x8*)(qrow + kc * 32);
            bf16x8 v;
#pragma unroll
            for (int j = 0; j < 8; ++j) v[j] = (__bf16)(bf2f(raw[j]) * 0.125f);
            qf[kc] = v;
        }
    }

    const __bf16* kpw = Kp + ((size_t)bh * 16 * 8 + w) * 512 + lane * 8;
    const __bf16* vpw = Vp + ((size_t)bh * 16 * 8 + w) * 512 + lane * 8;

    float m_l = -1e30f, l_l = 0.f;
    f32x4 oacc[4] = {};

    __builtin_amdgcn_global_load_lds(
        (const __attribute__((address_space(1))) unsigned int*)(kpw),
        (__attribute__((address_space(3))) unsigned int*)(&Slds[0][0][w * 512]),
        16, 0, 0);
    __builtin_amdgcn_global_load_lds(
        (const __attribute__((address_space(1))) unsigned int*)(vpw),
        (__attribute__((address_space(3))) unsigned int*)(&Slds[0][1][w * 512]),
        16, 0, 0);

#pragma unroll 2
    for (int kt = 0; kt < S_ / 64; ++kt) {
        const int cur = kt & 1;
        __syncthreads();
        if (kt < S_ / 64 - 1) {
            const size_t fo = (size_t)(kt + 1) * 8 * 512;
            __builtin_amdgcn_global_load_lds(
                (const __attribute__((address_space(1))) unsigned int*)(kpw + fo),
                (__attribute__((address_space(3))) unsigned int*)(
                    &Slds[cur ^ 1][0][w * 512]), 16, 0, 0);
            __builtin_amdgcn_global_load_lds(
                (const __attribute__((address_space(1))) unsigned int*)(vpw + fo),
                (__attribute__((address_space(3))) unsigned int*)(
                    &Slds[cur ^ 1][1][w * 512]), 16, 0, 0);
        }
        const __bf16* kl = &Slds[cur][0][0];
        const __bf16* vl = &Slds[cur][1][0];
        f32x4 s[4];
#pragma unroll
        for (int kb = 0; kb < 4; ++kb) {
            const bf16x8 k0 = *(const bf16x8*)(kl + (kb * 2 + 0) * 512 + lane * 8);
            const bf16x8 k1 = *(const bf16x8*)(kl + (kb * 2 + 1) * 512 + lane * 8);
            f32x4 z = {};
            z = __builtin_amdgcn_mfma_f32_16x16x32_bf16(k0, qf[0], z, 0, 0, 0);
            s[kb] = __builtin_amdgcn_mfma_f32_16x16x32_bf16(k1, qf[1], z, 0, 0, 0);
        }
        float mx0 = fmaxf(fmaxf(s[0][0], s[0][1]), fmaxf(s[0][2], s[0][3]));
        float mx1 = fmaxf(fmaxf(s[1][0], s[1][1]), fmaxf(s[1][2], s[1][3]));
        float mx2 = fmaxf(fmaxf(s[2][0], s[2][1]), fmaxf(s[2][2], s[2][3]));
        float mx3 = fmaxf(fmaxf(s[3][0], s[3][1]), fmaxf(s[3][2], s[3][3]));
        float mx = fmaxf(fmaxf(mx0, mx1), fmaxf(mx2, mx3));
        mx = fmaxf(mx, __shfl_xor(mx, 16));
        mx = fmaxf(mx, __shfl_xor(mx, 32));
        const float mnew = fmaxf(m_l, mx);
        const float corr = __expf(m_l - mnew);
        float p[4][4];
        float rs = 0.f;
#pragma unroll
        for (int kb = 0; kb < 4; ++kb) {
            float sb = 0.f;
#pragma unroll
            for (int r = 0; r < 4; ++r) {
                p[kb][r] = __expf(s[kb][r] - mnew);
                sb += p[kb][r];
            }
            rs += sb;
        }
        rs += __shfl_xor(rs, 16);
        rs += __shfl_xor(rs, 32);
        l_l = l_l * corr + rs;
        m_l = mnew;
#pragma unroll
        for (int db = 0; db < 4; ++db)
#pragma unroll
            for (int r = 0; r < 4; ++r) oacc[db][r] *= corr;
        bf16x8 pf[2];
#pragma unroll
        for (int kc = 0; kc < 2; ++kc) {
            bf16x8 v;
#pragma unroll
            for (int r = 0; r < 4; ++r) {
                v[r] = (__bf16)p[kc * 2][r];
                v[r + 4] = (__bf16)p[kc * 2 + 1][r];
            }
            pf[kc] = v;
        }
#pragma unroll
        for (int db = 0; db < 4; ++db) {
            const bf16x8 v0 = *(const bf16x8*)(vl + (db * 2 + 0) * 512 + lane * 8);
            const bf16x8 v1 = *(const bf16x8*)(vl + (db * 2 + 1) * 512 + lane * 8);
            oacc[db] = __builtin_amdgcn_mfma_f32_16x16x32_bf16(v0, pf[0], oacc[db], 0, 0, 0);
            oacc[db] = __builtin_amdgcn_mfma_f32_16x16x32_bf16(v1, pf[1], oacc[db], 0, 0, 0);
        }
    }
    const float inv_l = 1.f / l_l;
    __bf16* orow = O + (size_t)(bb * S_ + q0 + l15) * E_ + hh * 64 + lhi * 4;
#pragma unroll
    for (int db = 0; db < 4; ++db) {
        bf16x4 ov;
#pragma unroll
        for (int r = 0; r < 4; ++r) ov[r] = (__bf16)(oacc[db][r] * inv_l);
        *(bf16x4*)(orow + db * 16) = ov;
    }
}

// ---------------------------------------------------------------------------
// out[m] = bf16 x[m,:] . f32 W_out + b_out -> f32. One wave per row.
// ---------------------------------------------------------------------------
__global__ __launch_bounds__(256) void final_proj(
    const __bf16* __restrict__ X, const float* __restrict__ Wout,
    const float* __restrict__ bout, float* __restrict__ out) {
    const int wid = threadIdx.x >> 6, lane = threadIdx.x & 63;
    const int m = blockIdx.x * 4 + wid;
    const __bf16* xrow = X + (size_t)m * E_;
    float acc = 0.f;
#pragma unroll
    for (int c = 0; c < 2; ++c) {
        const int idx = c * 512 + lane * 8;
        const u16x8 xv = *(const u16x8*)(xrow + idx);
        const float4 w1 = *(const float4*)(Wout + idx);
        const float4 w2 = *(const float4*)(Wout + idx + 4);
        acc += bf2f(xv[0]) * w1.x + bf2f(xv[1]) * w1.y + bf2f(xv[2]) * w1.z +
               bf2f(xv[3]) * w1.w + bf2f(xv[4]) * w2.x + bf2f(xv[5]) * w2.y +
               bf2f(xv[6]) * w2.z + bf2f(xv[7]) * w2.w;
    }
#pragma unroll
    for (int off = 32; off; off >>= 1) acc += __shfl_xor(acc, off, 64);
    if (lane == 0) out[m] = acc + bout[0];
}

extern "C" void kernel_launch(void* const* d_in, const int* in_sizes, int n_in,
                              void* d_out, int out_size, void* d_ws, size_t ws_size,
                              hipStream_t stream) {
    const int* item_inputs = (const int*)d_in[0];
    const int* skill_inputs = (const int*)d_in[1];
    const float* emb_item = (const float*)d_in[5];
    const float* emb_skill = (const float*)d_in[6];
    const float* W_in = (const float*)d_in[7];
    const float* b_in = (const float*)d_in[8];
    const float* Wq = (const float*)d_in[9];
    const float* bq = (const float*)d_in[10];
    const float* Wk = (const float*)d_in[11];
    const float* bk = (const float*)d_in[12];
    const float* Wv = (const float*)d_in[13];
    const float* bv = (const float*)d_in[14];
    // d_in[15] Wg, d_in[16] bg: softmax-invariant, skipped.
    const float* pos_key = (const float*)d_in[17];
    const float* Wl = (const float*)d_in[18];
    const float* bl = (const float*)d_in[19];
    const float* W_out = (const float*)d_in[20];
    const float* b_out = (const float*)d_in[21];
    float* out = (float*)d_out;

    const size_t SZ = (size_t)M_ * E_;  // 4M
    __bf16* Xc = (__bf16*)d_ws;         // 8M elems
    __bf16* X = Xc + (size_t)M_ * 2048;
    __bf16* Qb = X + SZ;
    __bf16* Kp = Qb + SZ;               // packed K fragments / MLP scratch
    __bf16* Vp = Kp + SZ;               // packed V fragments
    __bf16* Winb = Vp + SZ;             // 2M elems
    __bf16* Wall = Winb + 2 * EE;       // 24M elems

    const dim3 gg64(16, 64);            // 64x64 tiles: 1024 blocks
    const dim3 ggkv(32, 32);            // kv direct: 1024 blocks
    const dim3 bb(256);

    embed_gather<<<dim3(M_), bb, 0, stream>>>(item_inputs, skill_inputs,
                                              emb_item, emb_skill, Xc);
    cvt_f32_bf16<<<dim3(2 * EE / 2048), bb, 0, stream>>>(W_in, Winb, 2 * EE);
    cvt_all_weights<<<dim3(L_ * 6 * EE / 2048), bb, 0, stream>>>(Wq, Wk, Wv, Wl, Wall);

    gemm64<0><<<gg64, bb, 0, stream>>>(Xc, Winb, b_in, X, 2048);

    for (int l = 0; l < L_; ++l) {
        __bf16* Wbuf = Wall + (size_t)l * 6 * EE;
        const float* pe_l = pos_key + (size_t)l * S_ * D_;
        gemm64<0><<<gg64, bb, 0, stream>>>(X, Wbuf + 0 * EE, bq + l * E_, Qb, E_);
        gemm_kv<<<ggkv, bb, 0, stream>>>(Qb, Wbuf + 1 * EE, bk + l * E_, Kp, E_,
                                         pe_l, bv + l * E_);
        attn_mfma<<<dim3(S_ / 128, B_ * H_), dim3(512), 0, stream>>>(Qb, Kp, Vp, X);
        gemm64<1><<<gg64, bb, 0, stream>>>(X, Wbuf + 3 * EE, bl + (l * 3 + 0) * E_, Qb, E_);
        gemm64<1><<<gg64, bb, 0, stream>>>(Qb, Wbuf + 4 * EE, bl + (l * 3 + 1) * E_, Kp, E_);
        gemm64<1><<<gg64, bb, 0, stream>>>(Kp, Wbuf + 5 * EE, bl + (l * 3 + 2) * E_, X, E_);
    }
    final_proj<<<dim3(M_ / 4), bb, 0, stream>>>(X, W_out, b_out, out);
}